// Round 3
// baseline (479.753 us; speedup 1.0000x reference)
//
#include <hip/hip_runtime.h>
#include <hip/hip_bf16.h>

typedef unsigned short u16;
typedef __attribute__((ext_vector_type(8))) short short8;
typedef __attribute__((ext_vector_type(4))) float floatx4;

#define NROWS 8192
#define DIM 256
#define BM 128
#define BN 128
#define BK 32
#define GRID 768          // 3 blocks/CU x 256 CUs, pinned by __launch_bounds__(256,3)
#define NTILES 4096       // (8192/128)^2

__device__ __forceinline__ void atomicMinFloat(float* addr, float val) {
    if (val >= 0.0f) {
        atomicMin((int*)addr, __float_as_int(val));
    } else {
        atomicMax((unsigned int*)addr, __float_as_uint(val));
    }
}

__device__ __forceinline__ u16 f32_to_bf16_rne(float x) {
    unsigned int u = __float_as_uint(x);
    unsigned int r = (u + 0x7fffu + ((u >> 16) & 1u)) >> 16;
    return (u16)r;
}

// C(M) = -logp * exp(logp), logp = -0.5*((M-1)/sigma)^2 - ln(sigma) - 0.5 ln(2pi)
// Quasiconcave in M => row-min over a set = min(C(min M), C(max M)).
__device__ __forceinline__ float c_of_m(float m) {
    const float INV_SIG = 1.0f / 0.3f;
    const float KC = 0.28503427f;  // -ln(0.3) - 0.5*ln(2*pi)
    float z = (m - 1.0f) * INV_SIG;
    float logp = fmaf(-0.5f * z, z, KC);
    return -logp * __expf(logp);
}

// 16B async DMA global -> LDS. LDS dest is wave-uniform base + lane*16.
__device__ __forceinline__ void load16(const u16* g, u16* l) {
    __builtin_amdgcn_global_load_lds(
        (__attribute__((address_space(1))) void*)g,
        (__attribute__((address_space(3))) void*)l, 16, 0, 0);
}

// Wave-per-row normalize: 4 rows/block, float4 loads, shuffle reduce, bf16 out.
// Also initializes out[] to +inf (fused init).
__global__ __launch_bounds__(256) void normalize_kernel(const float* __restrict__ Ex,
                                                        const float* __restrict__ Ey,
                                                        u16* __restrict__ Xn,
                                                        u16* __restrict__ Yn,
                                                        float* __restrict__ out) {
    const int t = threadIdx.x;
    const int lane = t & 63;
    const int row = blockIdx.x * 4 + (t >> 6);
    const float* src = (blockIdx.y == 0) ? Ex : Ey;
    u16* dst = (blockIdx.y == 0) ? Xn : Yn;

    float4 v = *(const float4*)(src + (size_t)row * DIM + lane * 4);
    float s = fmaf(v.x, v.x, fmaf(v.y, v.y, fmaf(v.z, v.z, v.w * v.w)));
    #pragma unroll
    for (int m = 32; m >= 1; m >>= 1) s += __shfl_xor(s, m, 64);
    float inv = 1.0f / fmaxf(sqrtf(s), 1e-8f);

    ushort4 o;
    o.x = f32_to_bf16_rne(v.x * inv);
    o.y = f32_to_bf16_rne(v.y * inv);
    o.z = f32_to_bf16_rne(v.z * inv);
    o.w = f32_to_bf16_rne(v.w * inv);
    *(ushort4*)(dst + (size_t)row * DIM + lane * 4) = o;

    if (blockIdx.y == 0 && lane == 0) out[row] = __uint_as_float(0x7f800000u);  // +inf
}

// Persistent-block GEMM. 768 blocks (3/CU), each loops over tiles
// t = bid, bid+768, ... Each tile: 128x128, BK=32, 8 K-steps, double-buffered
// LDS staged via global_load_lds (16B, xor-swizzled piece layout -> b128
// fragment reads are 2-way-conflict-free). The step stream is uniform ACROSS
// tiles: during step kt we prefetch step kt+1's buffer, and at kt=7 we
// prefetch the NEXT tile's first buffer, so the DMA pipeline never drains at
// tile boundaries. Epilogue (register-only, no LDS) overlaps that prefetch.
__global__ __launch_bounds__(256, 3) void gemm_min_kernel(const u16* __restrict__ Xn,
                                                          const u16* __restrict__ Yn,
                                                          float* __restrict__ out) {
    __shared__ u16 As[2][BM * BK];  // 2 x 8 KB
    __shared__ u16 Bs[2][BN * BK];  // 2 x 8 KB

    const int tid = threadIdx.x;
    const int w = tid >> 6;
    const int lane = tid & 63;
    const int wr = w >> 1;
    const int wc = w & 1;
    const int lq = lane >> 4;
    const int lm = lane & 15;
    const int swz = (lm >> 1) & 3;

    // Staging lane constants: chunk s (16B) -> row s>>2, piece (s&3)^((row>>1)&3)
    const int s0 = w * 64 + lane;
    const int s1 = s0 + 256;
    const int r0 = s0 >> 2, p0 = (s0 & 3) ^ ((r0 >> 1) & 3);
    const int r1 = s1 >> 2, p1 = (s1 & 3) ^ ((r1 >> 1) & 3);
    const int go0 = r0 * DIM + p0 * 8;   // global element offset within tile
    const int go1 = r1 * DIM + p1 * 8;
    const int lo0 = (w * 64) * 8;        // wave-uniform LDS element base, i=0
    const int lo1 = (256 + w * 64) * 8;  // i=1

    // Fragment read offsets (elements), per-lane constants
    int aoff[4], boff[4];
    #pragma unroll
    for (int rg = 0; rg < 4; ++rg)
        aoff[rg] = ((wr * 64 + rg * 16 + lm) * 4 + (lq ^ swz)) * 8;
    #pragma unroll
    for (int cg = 0; cg < 4; ++cg)
        boff[cg] = ((wc * 64 + cg * 16 + lm) * 4 + (lq ^ swz)) * 8;

    auto stage = [&](int rs, int cs, int k0, int b) {
        const u16* xb = Xn + (size_t)rs * DIM + k0;
        const u16* yb = Yn + (size_t)cs * DIM + k0;
        load16(xb + go0, &As[b][lo0]);
        load16(xb + go1, &As[b][lo1]);
        load16(yb + go0, &Bs[b][lo0]);
        load16(yb + go1, &Bs[b][lo1]);
    };

    int t = blockIdx.x;
    stage((t >> 6) * BM, (t & 63) * BN, 0, 0);  // prologue: first buffer

    while (t < NTILES) {
        const int rowStart = (t >> 6) * BM;
        const int colStart = (t & 63) * BN;

        floatx4 acc[4][4];
        #pragma unroll
        for (int i = 0; i < 4; ++i)
            #pragma unroll
            for (int j = 0; j < 4; ++j)
                acc[i][j] = (floatx4){0.0f, 0.0f, 0.0f, 0.0f};

        #pragma unroll
        for (int kt = 0; kt < DIM / BK; ++kt) {
            __syncthreads();  // compiler vmcnt(0) drains exactly step-kt's DMA
            if (kt < DIM / BK - 1) {
                stage(rowStart, colStart, (kt + 1) * BK, (kt + 1) & 1);
            } else if (t + GRID < NTILES) {
                const int nt = t + GRID;
                stage((nt >> 6) * BM, (nt & 63) * BN, 0, 0);  // next tile, buf 0
            }

            const int cur = kt & 1;
            short8 a[4], b[4];
            #pragma unroll
            for (int rg = 0; rg < 4; ++rg)
                a[rg] = *(const short8*)(&As[cur][aoff[rg]]);
            #pragma unroll
            for (int cg = 0; cg < 4; ++cg)
                b[cg] = *(const short8*)(&Bs[cur][boff[cg]]);

            #pragma unroll
            for (int rg = 0; rg < 4; ++rg)
                #pragma unroll
                for (int cg = 0; cg < 4; ++cg)
                    acc[rg][cg] = __builtin_amdgcn_mfma_f32_16x16x32_bf16(a[rg], b[cg], acc[rg][cg], 0, 0, 0);
        }

        // Epilogue (register-only; overlaps the cross-tile prefetch in flight).
        #pragma unroll
        for (int rg = 0; rg < 4; ++rg) {
            #pragma unroll
            for (int r = 0; r < 4; ++r) {
                float mn = acc[rg][0][r];
                float mx = mn;
                #pragma unroll
                for (int cg = 1; cg < 4; ++cg) {
                    float m = acc[rg][cg][r];
                    mn = fminf(mn, m);
                    mx = fmaxf(mx, m);
                }
                #pragma unroll
                for (int mofs = 1; mofs < 16; mofs <<= 1) {
                    mn = fminf(mn, __shfl_xor(mn, mofs, 64));
                    mx = fmaxf(mx, __shfl_xor(mx, mofs, 64));
                }
                float cmin = fminf(c_of_m(mn), c_of_m(mx));
                if (lm == 0) {
                    int row = rowStart + wr * 64 + rg * 16 + lq * 4 + r;
                    // out[] only decreases over time, so a (possibly stale)
                    // plain read >= truth -> guard is race-safe and cuts
                    // atomic RMW write traffic ~8x.
                    if (cmin < out[row]) atomicMinFloat(&out[row], cmin);
                }
            }
        }

        t += GRID;
    }
}

extern "C" void kernel_launch(void* const* d_in, const int* in_sizes, int n_in,
                              void* d_out, int out_size, void* d_ws, size_t ws_size,
                              hipStream_t stream) {
    const float* Ex = (const float*)d_in[0];
    const float* Ey = (const float*)d_in[1];
    float* out = (float*)d_out;
    u16* Xn = (u16*)d_ws;                // 4 MB
    u16* Yn = Xn + (size_t)NROWS * DIM;  // 4 MB

    hipLaunchKernelGGL(normalize_kernel, dim3(NROWS / 4, 2), dim3(256), 0, stream,
                       Ex, Ey, Xn, Yn, out);
    hipLaunchKernelGGL(gemm_min_kernel, dim3(GRID), dim3(256), 0, stream,
                       Xn, Yn, out);
}

// Round 4
// 270.526 us; speedup vs baseline: 1.7734x; 1.7734x over previous
//
#include <hip/hip_runtime.h>
#include <hip/hip_bf16.h>

typedef unsigned short u16;
typedef __attribute__((ext_vector_type(8))) short short8;
typedef __attribute__((ext_vector_type(4))) float floatx4;

#define NROWS 8192
#define DIM 256
#define BM 128
#define BN 128
#define BK 32
#define NKB 8   // DIM / BK

__device__ __forceinline__ void atomicMinFloat(float* addr, float val) {
    if (val >= 0.0f) {
        atomicMin((int*)addr, __float_as_int(val));
    } else {
        atomicMax((unsigned int*)addr, __float_as_uint(val));
    }
}

__device__ __forceinline__ u16 f32_to_bf16_rne(float x) {
    unsigned int u = __float_as_uint(x);
    unsigned int r = (u + 0x7fffu + ((u >> 16) & 1u)) >> 16;
    return (u16)r;
}

// C(M) = -logp * exp(logp); quasiconcave in M => rowmin = min(C(minM), C(maxM)).
__device__ __forceinline__ float c_of_m(float m) {
    const float INV_SIG = 1.0f / 0.3f;
    const float KC = 0.28503427f;  // -ln(0.3) - 0.5*ln(2*pi)
    float z = (m - 1.0f) * INV_SIG;
    float logp = fmaf(-0.5f * z, z, KC);
    return -logp * __expf(logp);
}

// 16B async DMA global -> LDS. LDS dest is wave-uniform base + lane*16.
__device__ __forceinline__ void load16(const u16* g, u16* l) {
    __builtin_amdgcn_global_load_lds(
        (__attribute__((address_space(1))) void*)g,
        (__attribute__((address_space(3))) void*)l, 16, 0, 0);
}

// Wave-per-row normalize: 4 rows/block, float4 loads, shuffle reduce, bf16 out.
// Also initializes out[] to +inf (fused init).
__global__ __launch_bounds__(256) void normalize_kernel(const float* __restrict__ Ex,
                                                        const float* __restrict__ Ey,
                                                        u16* __restrict__ Xn,
                                                        u16* __restrict__ Yn,
                                                        float* __restrict__ out) {
    const int t = threadIdx.x;
    const int lane = t & 63;
    const int row = blockIdx.x * 4 + (t >> 6);
    const float* src = (blockIdx.y == 0) ? Ex : Ey;
    u16* dst = (blockIdx.y == 0) ? Xn : Yn;

    float4 v = *(const float4*)(src + (size_t)row * DIM + lane * 4);
    float s = fmaf(v.x, v.x, fmaf(v.y, v.y, fmaf(v.z, v.z, v.w * v.w)));
    #pragma unroll
    for (int m = 32; m >= 1; m >>= 1) s += __shfl_xor(s, m, 64);
    float inv = 1.0f / fmaxf(sqrtf(s), 1e-8f);

    ushort4 o;
    o.x = f32_to_bf16_rne(v.x * inv);
    o.y = f32_to_bf16_rne(v.y * inv);
    o.z = f32_to_bf16_rne(v.z * inv);
    o.w = f32_to_bf16_rne(v.w * inv);
    *(ushort4*)(dst + (size_t)row * DIM + lane * 4) = o;

    if (blockIdx.y == 0 && lane == 0) out[row] = __uint_as_float(0x7f800000u);  // +inf
}

// One-shot GEMM tile: stage the FULL-K 128x256 A and B tiles (64+64 KB LDS)
// with 16 global_load_lds DMAs per thread, ONE barrier, then 8 unrolled
// K-steps of ds_read_b128 + MFMA with no further barriers. This removes the
// per-step barrier->vmcnt(0)->DMA-latency chain that bounded R1/R2 (~1900
// cyc/step). 512 threads = 8 waves (2/SIMD) so DMA issue and compute overlap
// within the CU even at 1 block/CU (128 KB LDS of the 160 KB pool).
// Wave w: rows (w>>2)*64..+64, cols (w&3)*32..+32 -> 4x2 grid of 16x16x32.
__global__ __launch_bounds__(512) void gemm_min_kernel(const u16* __restrict__ Xn,
                                                       const u16* __restrict__ Yn,
                                                       float* __restrict__ out) {
    __shared__ u16 As[NKB][BM * BK];  // 64 KB
    __shared__ u16 Bs[NKB][BN * BK];  // 64 KB

    const int tid = threadIdx.x;
    const int w = tid >> 6;
    const int lane = tid & 63;
    const int wr = w >> 2;   // 0..1 -> 64 rows
    const int wc = w & 3;    // 0..3 -> 32 cols
    const int lq = lane >> 4;
    const int lm = lane & 15;
    const int swz = (lm >> 1) & 3;

    const int t = blockIdx.x;
    const int rowStart = (t >> 6) * BM;
    const int colStart = (t & 63) * BN;

    // Staging: per kb-tile (128x32 = 512 16B-chunks), wave w owns chunks
    // [w*64, w*64+64). Chunk s -> row s>>2, piece (s&3)^((row>>1)&3) (xor
    // swizzle keeps ds_read_b128 fragment reads 2-way-conflict-free).
    const int s = w * 64 + lane;
    const int srow = s >> 2;
    const int spg = (s & 3) ^ ((srow >> 1) & 3);
    const u16* xb = Xn + (size_t)(rowStart + srow) * DIM + spg * 8;
    const u16* yb = Yn + (size_t)(colStart + srow) * DIM + spg * 8;
    const int lbase = (w * 64) * 8;  // wave-uniform LDS element base

    #pragma unroll
    for (int kb = 0; kb < NKB; ++kb) {
        load16(xb + kb * BK, &As[kb][lbase]);
        load16(yb + kb * BK, &Bs[kb][lbase]);
    }
    __syncthreads();  // the ONLY barrier: drains all 16 DMAs at once

    floatx4 acc[4][2];
    #pragma unroll
    for (int i = 0; i < 4; ++i)
        #pragma unroll
        for (int j = 0; j < 2; ++j)
            acc[i][j] = (floatx4){0.0f, 0.0f, 0.0f, 0.0f};

    #pragma unroll
    for (int kt = 0; kt < NKB; ++kt) {
        short8 a[4], b[2];
        #pragma unroll
        for (int rg = 0; rg < 4; ++rg)
            a[rg] = *(const short8*)(&As[kt][((wr * 64 + rg * 16 + lm) * 4 + (lq ^ swz)) * 8]);
        #pragma unroll
        for (int cg = 0; cg < 2; ++cg)
            b[cg] = *(const short8*)(&Bs[kt][((wc * 32 + cg * 16 + lm) * 4 + (lq ^ swz)) * 8]);

        #pragma unroll
        for (int rg = 0; rg < 4; ++rg)
            #pragma unroll
            for (int cg = 0; cg < 2; ++cg)
                acc[rg][cg] = __builtin_amdgcn_mfma_f32_16x16x32_bf16(a[rg], b[cg], acc[rg][cg], 0, 0, 0);
    }

    // Epilogue: row min/max of M over this wave's 32 columns; C is
    // quasiconcave in M. Fire-and-forget atomics (NO read guard -- R3's
    // guard read serialized on contended coherent lines, 4.3x regression).
    #pragma unroll
    for (int rg = 0; rg < 4; ++rg) {
        #pragma unroll
        for (int r = 0; r < 4; ++r) {
            float mn = acc[rg][0][r];
            float mx = mn;
            {
                float m = acc[rg][1][r];
                mn = fminf(mn, m);
                mx = fmaxf(mx, m);
            }
            #pragma unroll
            for (int mofs = 1; mofs < 16; mofs <<= 1) {
                mn = fminf(mn, __shfl_xor(mn, mofs, 64));
                mx = fmaxf(mx, __shfl_xor(mx, mofs, 64));
            }
            if (lm == 0) {
                float cmin = fminf(c_of_m(mn), c_of_m(mx));
                int row = rowStart + wr * 64 + rg * 16 + lq * 4 + r;
                atomicMinFloat(&out[row], cmin);
            }
        }
    }
}

extern "C" void kernel_launch(void* const* d_in, const int* in_sizes, int n_in,
                              void* d_out, int out_size, void* d_ws, size_t ws_size,
                              hipStream_t stream) {
    const float* Ex = (const float*)d_in[0];
    const float* Ey = (const float*)d_in[1];
    float* out = (float*)d_out;
    u16* Xn = (u16*)d_ws;                // 4 MB
    u16* Yn = Xn + (size_t)NROWS * DIM;  // 4 MB

    hipLaunchKernelGGL(normalize_kernel, dim3(NROWS / 4, 2), dim3(256), 0, stream,
                       Ex, Ey, Xn, Yn, out);
    hipLaunchKernelGGL(gemm_min_kernel, dim3((NROWS / BM) * (NROWS / BN)), dim3(512), 0, stream,
                       Xn, Yn, out);
}

// Round 5
// 180.425 us; speedup vs baseline: 2.6590x; 1.4994x over previous
//
#include <hip/hip_runtime.h>
#include <hip/hip_bf16.h>

typedef unsigned short u16;
typedef __attribute__((ext_vector_type(8))) short short8;
typedef __attribute__((ext_vector_type(4))) float floatx4;

#define NROWS 8192
#define DIM 256
#define NKB 8   // DIM / 32 k-chunks per row
#define BM 128
#define BN 128

__device__ __forceinline__ void atomicMinFloat(float* addr, float val) {
    if (val >= 0.0f) {
        atomicMin((int*)addr, __float_as_int(val));
    } else {
        atomicMax((unsigned int*)addr, __float_as_uint(val));
    }
}

__device__ __forceinline__ u16 f32_to_bf16_rne(float x) {
    unsigned int u = __float_as_uint(x);
    unsigned int r = (u + 0x7fffu + ((u >> 16) & 1u)) >> 16;
    return (u16)r;
}

// C(M) = -logp * exp(logp); quasiconcave in M => rowmin = min(C(minM), C(maxM)).
__device__ __forceinline__ float c_of_m(float m) {
    const float INV_SIG = 1.0f / 0.3f;
    const float KC = 0.28503427f;  // -ln(0.3) - 0.5*ln(2*pi)
    float z = (m - 1.0f) * INV_SIG;
    float logp = fmaf(-0.5f * z, z, KC);
    return -logp * __expf(logp);
}

// Normalize rows AND store directly in MFMA-fragment ("panel") layout:
// element (row r, k) -> flat[ ((p*8+kt)*64 + lq*16 + lm)*8 + j ]
//   p = r>>4, lm = r&15, kt = k>>5, lq = (k>>3)&3, j = k&7.
// A wave's fragment load in the GEMM is then base + lane*16B: one fully
// coalesced global_load_dwordx4 per fragment. No LDS anywhere.
// Wave per row; lane ln holds k = 4*ln..4*ln+3. Also inits out[] = +inf.
__global__ __launch_bounds__(256) void normalize_kernel(const float* __restrict__ Ex,
                                                        const float* __restrict__ Ey,
                                                        u16* __restrict__ Xs,
                                                        u16* __restrict__ Ys,
                                                        float* __restrict__ out) {
    const int t = threadIdx.x;
    const int ln = t & 63;
    const int row = blockIdx.x * 4 + (t >> 6);
    const float* src = (blockIdx.y == 0) ? Ex : Ey;
    u16* dst = (blockIdx.y == 0) ? Xs : Ys;

    float4 v = *(const float4*)(src + (size_t)row * DIM + ln * 4);
    float s = fmaf(v.x, v.x, fmaf(v.y, v.y, fmaf(v.z, v.z, v.w * v.w)));
    #pragma unroll
    for (int m = 32; m >= 1; m >>= 1) s += __shfl_xor(s, m, 64);
    float inv = 1.0f / fmaxf(sqrtf(s), 1e-8f);

    ushort4 o;
    o.x = f32_to_bf16_rne(v.x * inv);
    o.y = f32_to_bf16_rne(v.y * inv);
    o.z = f32_to_bf16_rne(v.z * inv);
    o.w = f32_to_bf16_rne(v.w * inv);

    const int p = row >> 4;
    const int lm = row & 15;
    const int kt = ln >> 3;
    const int lq = (ln >> 1) & 3;
    const int j4 = (ln & 1) * 4;
    const size_t off = ((size_t)((p * NKB + kt) * 64 + lq * 16 + lm)) * 8 + j4;
    *(ushort4*)(dst + off) = o;

    if (blockIdx.y == 0 && ln == 0) out[row] = __uint_as_float(0x7f800000u);  // +inf
}

// LDS-free GEMM: fragments load straight from the panel-layout arrays
// (L2-resident, 8 MB total) into registers. No barriers, no ds_read, no
// staging address math -- waves are fully independent; the compiler
// software-pipelines the 64 coalesced dwordx4 loads against 128 MFMAs via
// vmcnt. Block = 256 thr, 2x2 waves of 64x64 (4x4 grid of 16x16x32 bf16).
// Epilogue: C quasiconcave in M -> row min/max of M, eval C twice,
// fire-and-forget atomicMin (no read guard -- see R3 post-mortem).
__global__ __launch_bounds__(256) void gemm_min_kernel(const u16* __restrict__ Xs,
                                                       const u16* __restrict__ Ys,
                                                       float* __restrict__ out) {
    const int tid = threadIdx.x;
    const int w = tid >> 6;
    const int lane = tid & 63;
    const int wr = w >> 1;
    const int wc = w & 1;
    const int lq = lane >> 4;
    const int lm = lane & 15;

    const int rowPan0 = blockIdx.y * (BM / 16) + wr * 4;  // first A panel
    const int colPan0 = blockIdx.x * (BN / 16) + wc * 4;  // first B panel

    // Per-lane fragment pointers: panel p, chunk kt lives at
    // ((p*8 + kt)*64 + lane) * 16 bytes.
    const u16* ax = Xs + ((size_t)rowPan0 * NKB * 64 + lane) * 8;
    const u16* bx = Ys + ((size_t)colPan0 * NKB * 64 + lane) * 8;

    floatx4 acc[4][4];
    #pragma unroll
    for (int i = 0; i < 4; ++i)
        #pragma unroll
        for (int j = 0; j < 4; ++j)
            acc[i][j] = (floatx4){0.0f, 0.0f, 0.0f, 0.0f};

    #pragma unroll
    for (int kt = 0; kt < NKB; ++kt) {
        short8 a[4], b[4];
        #pragma unroll
        for (int rg = 0; rg < 4; ++rg)
            a[rg] = *(const short8*)(ax + (size_t)(rg * NKB + kt) * 64 * 8);
        #pragma unroll
        for (int cg = 0; cg < 4; ++cg)
            b[cg] = *(const short8*)(bx + (size_t)(cg * NKB + kt) * 64 * 8);

        #pragma unroll
        for (int rg = 0; rg < 4; ++rg)
            #pragma unroll
            for (int cg = 0; cg < 4; ++cg)
                acc[rg][cg] = __builtin_amdgcn_mfma_f32_16x16x32_bf16(a[rg], b[cg], acc[rg][cg], 0, 0, 0);
    }

    // Row min/max of M over this wave's 64 columns.
    #pragma unroll
    for (int rg = 0; rg < 4; ++rg) {
        #pragma unroll
        for (int r = 0; r < 4; ++r) {
            float mn = acc[rg][0][r];
            float mx = mn;
            #pragma unroll
            for (int cg = 1; cg < 4; ++cg) {
                float m = acc[rg][cg][r];
                mn = fminf(mn, m);
                mx = fmaxf(mx, m);
            }
            #pragma unroll
            for (int mofs = 1; mofs < 16; mofs <<= 1) {
                mn = fminf(mn, __shfl_xor(mn, mofs, 64));
                mx = fmaxf(mx, __shfl_xor(mx, mofs, 64));
            }
            if (lm == 0) {
                float cmin = fminf(c_of_m(mn), c_of_m(mx));
                int row = (rowPan0 + rg) * 16 + lq * 4 + r;
                atomicMinFloat(&out[row], cmin);
            }
        }
    }
}

extern "C" void kernel_launch(void* const* d_in, const int* in_sizes, int n_in,
                              void* d_out, int out_size, void* d_ws, size_t ws_size,
                              hipStream_t stream) {
    const float* Ex = (const float*)d_in[0];
    const float* Ey = (const float*)d_in[1];
    float* out = (float*)d_out;
    u16* Xs = (u16*)d_ws;                // 4 MB, panel layout
    u16* Ys = Xs + (size_t)NROWS * DIM;  // 4 MB, panel layout

    hipLaunchKernelGGL(normalize_kernel, dim3(NROWS / 4, 2), dim3(256), 0, stream,
                       Ex, Ey, Xs, Ys, out);
    hipLaunchKernelGGL(gemm_min_kernel, dim3(NROWS / BN, NROWS / BM), dim3(256), 0, stream,
                       Xs, Ys, out);
}

// Round 6
// 109.034 us; speedup vs baseline: 4.4000x; 1.6547x over previous
//
#include <hip/hip_runtime.h>
#include <hip/hip_bf16.h>

typedef unsigned short u16;
typedef __attribute__((ext_vector_type(8))) short short8;
typedef __attribute__((ext_vector_type(4))) float floatx4;

#define NROWS 8192
#define DIM 256
#define BM 128        // rows per block
#define BNT 128       // cols per col-tile
#define NCT 4         // col-tiles per block -> 512 cols
#define NKB 8         // K-steps (BK=32)
#define BK 32

__device__ __forceinline__ void atomicMinFloat(float* addr, float val) {
    if (val >= 0.0f) {
        atomicMin((int*)addr, __float_as_int(val));
    } else {
        atomicMax((unsigned int*)addr, __float_as_uint(val));
    }
}

__device__ __forceinline__ u16 f32_to_bf16_rne(float x) {
    unsigned int u = __float_as_uint(x);
    unsigned int r = (u + 0x7fffu + ((u >> 16) & 1u)) >> 16;
    return (u16)r;
}

// C(M) = -logp * exp(logp); quasiconcave in M => rowmin = min(C(minM), C(maxM)).
__device__ __forceinline__ float c_of_m(float m) {
    const float INV_SIG = 1.0f / 0.3f;
    const float KC = 0.28503427f;  // -ln(0.3) - 0.5*ln(2*pi)
    float z = (m - 1.0f) * INV_SIG;
    float logp = fmaf(-0.5f * z, z, KC);
    return -logp * __expf(logp);
}

// 16B async DMA global -> LDS. LDS dest is wave-uniform base + lane*16.
__device__ __forceinline__ void load16(const u16* g, u16* l) {
    __builtin_amdgcn_global_load_lds(
        (__attribute__((address_space(1))) void*)g,
        (__attribute__((address_space(3))) void*)l, 16, 0, 0);
}

// Wave-per-row normalize: 4 rows/block, float4 loads, shuffle reduce, bf16
// row-major out. Also initializes out[] to +inf.
__global__ __launch_bounds__(256) void normalize_kernel(const float* __restrict__ Ex,
                                                        const float* __restrict__ Ey,
                                                        u16* __restrict__ Xn,
                                                        u16* __restrict__ Yn,
                                                        float* __restrict__ out) {
    const int t = threadIdx.x;
    const int lane = t & 63;
    const int row = blockIdx.x * 4 + (t >> 6);
    const float* src = (blockIdx.y == 0) ? Ex : Ey;
    u16* dst = (blockIdx.y == 0) ? Xn : Yn;

    float4 v = *(const float4*)(src + (size_t)row * DIM + lane * 4);
    float s = fmaf(v.x, v.x, fmaf(v.y, v.y, fmaf(v.z, v.z, v.w * v.w)));
    #pragma unroll
    for (int m = 32; m >= 1; m >>= 1) s += __shfl_xor(s, m, 64);
    float inv = 1.0f / fmaxf(sqrtf(s), 1e-8f);

    ushort4 o;
    o.x = f32_to_bf16_rne(v.x * inv);
    o.y = f32_to_bf16_rne(v.y * inv);
    o.z = f32_to_bf16_rne(v.z * inv);
    o.w = f32_to_bf16_rne(v.w * inv);
    *(ushort4*)(dst + (size_t)row * DIM + lane * 4) = o;

    if (blockIdx.y == 0 && lane == 0) out[row] = __uint_as_float(0x7f800000u);  // +inf
}

// Block = 128 rows x 512 cols: A (128x256, 64 KB) staged to LDS ONCE, then
// 4 col-tiles x 8 K-steps with only an 8 KB B-tile staged per step
// (double-buffered). 80 KB LDS -> 2 blocks/CU. Grid order: row = b&63 (XCD
// gets 8 fixed A-panels, L2-resident), colgroup = b>>6 (all XCDs share one
// 256 KB B-strip at a time). Row min/max of M carried in registers across
// col-tiles; single shuffle-epilogue + atomics at the end.
__global__ __launch_bounds__(256, 2) void gemm_min_kernel(const u16* __restrict__ Xn,
                                                          const u16* __restrict__ Yn,
                                                          float* __restrict__ out) {
    __shared__ u16 As[NKB][BM * BK];  // 64 KB, full-K A
    __shared__ u16 Bs[2][BNT * BK];   // 16 KB, double-buffered B

    const int tid = threadIdx.x;
    const int w = tid >> 6;
    const int lane = tid & 63;
    const int wr = w >> 1;
    const int wc = w & 1;
    const int lq = lane >> 4;
    const int lm = lane & 15;
    const int swz = (lm >> 1) & 3;

    const int b = blockIdx.x;
    const int rowStart = (b & 63) * BM;
    const int colBase = (b >> 6) * (NCT * BNT);

    // Staging constants: chunk s (16B) -> row s>>2, piece (s&3)^((row>>1)&3)
    // (xor swizzle keeps ds_read_b128 fragment reads 2-way-conflict-free).
    const int s0 = w * 64 + lane;
    const int s1 = s0 + 256;
    const int r0 = s0 >> 2, p0 = (s0 & 3) ^ ((r0 >> 1) & 3);
    const int r1 = s1 >> 2, p1 = (s1 & 3) ^ ((r1 >> 1) & 3);
    const int go0 = r0 * DIM + p0 * 8;   // global element offset within tile
    const int go1 = r1 * DIM + p1 * 8;
    const int lo0 = (w * 64) * 8;        // wave-uniform LDS element base
    const int lo1 = (256 + w * 64) * 8;

    // Prologue: full-K A + first B tile.
    {
        const u16* xb = Xn + (size_t)rowStart * DIM;
        #pragma unroll
        for (int kb = 0; kb < NKB; ++kb) {
            load16(xb + go0 + kb * BK, &As[kb][lo0]);
            load16(xb + go1 + kb * BK, &As[kb][lo1]);
        }
        const u16* yb = Yn + (size_t)colBase * DIM;
        load16(yb + go0, &Bs[0][lo0]);
        load16(yb + go1, &Bs[0][lo1]);
    }

    int aoff[4], boff[4];
    #pragma unroll
    for (int rg = 0; rg < 4; ++rg)
        aoff[rg] = ((wr * 64 + rg * 16 + lm) * 4 + (lq ^ swz)) * 8;
    #pragma unroll
    for (int cg = 0; cg < 4; ++cg)
        boff[cg] = ((wc * 64 + cg * 16 + lm) * 4 + (lq ^ swz)) * 8;

    floatx4 mn4[4], mx4[4];
    #pragma unroll
    for (int rg = 0; rg < 4; ++rg) {
        mn4[rg] = (floatx4){3.4e38f, 3.4e38f, 3.4e38f, 3.4e38f};
        mx4[rg] = (floatx4){-3.4e38f, -3.4e38f, -3.4e38f, -3.4e38f};
    }

    for (int ct = 0; ct < NCT; ++ct) {
        floatx4 acc[4][4];
        #pragma unroll
        for (int i = 0; i < 4; ++i)
            #pragma unroll
            for (int j = 0; j < 4; ++j)
                acc[i][j] = (floatx4){0.0f, 0.0f, 0.0f, 0.0f};

        #pragma unroll
        for (int kt = 0; kt < NKB; ++kt) {
            __syncthreads();  // drains only the previous step's 8 KB B-DMA
            if (!(ct == NCT - 1 && kt == NKB - 1)) {
                int nct = ct, nkt = kt + 1;
                if (nkt == NKB) { nkt = 0; nct = ct + 1; }
                const u16* yb = Yn + (size_t)(colBase + nct * BNT) * DIM + nkt * BK;
                load16(yb + go0, &Bs[nkt & 1][lo0]);
                load16(yb + go1, &Bs[nkt & 1][lo1]);
            }

            const int buf = kt & 1;
            short8 a[4], bb[4];
            #pragma unroll
            for (int rg = 0; rg < 4; ++rg)
                a[rg] = *(const short8*)(&As[kt][aoff[rg]]);
            #pragma unroll
            for (int cg = 0; cg < 4; ++cg)
                bb[cg] = *(const short8*)(&Bs[buf][boff[cg]]);

            #pragma unroll
            for (int rg = 0; rg < 4; ++rg)
                #pragma unroll
                for (int cg = 0; cg < 4; ++cg)
                    acc[rg][cg] = __builtin_amdgcn_mfma_f32_16x16x32_bf16(a[rg], bb[cg], acc[rg][cg], 0, 0, 0);
        }

        // Fold this col-tile into register-carried row min/max (no shuffles).
        #pragma unroll
        for (int rg = 0; rg < 4; ++rg)
            #pragma unroll
            for (int cg = 0; cg < 4; ++cg)
                #pragma unroll
                for (int r = 0; r < 4; ++r) {
                    float m = acc[rg][cg][r];
                    mn4[rg][r] = fminf(mn4[rg][r], m);
                    mx4[rg][r] = fmaxf(mx4[rg][r], m);
                }
    }

    // Single epilogue: reduce across the 16 lanes of the quad, eval C twice,
    // fire-and-forget atomicMin (no read guard -- see R3 post-mortem).
    #pragma unroll
    for (int rg = 0; rg < 4; ++rg) {
        #pragma unroll
        for (int r = 0; r < 4; ++r) {
            float mn = mn4[rg][r];
            float mx = mx4[rg][r];
            #pragma unroll
            for (int mofs = 1; mofs < 16; mofs <<= 1) {
                mn = fminf(mn, __shfl_xor(mn, mofs, 64));
                mx = fmaxf(mx, __shfl_xor(mx, mofs, 64));
            }
            if (lm == 0) {
                float cmin = fminf(c_of_m(mn), c_of_m(mx));
                int row = rowStart + wr * 64 + rg * 16 + lq * 4 + r;
                atomicMinFloat(&out[row], cmin);
            }
        }
    }
}

extern "C" void kernel_launch(void* const* d_in, const int* in_sizes, int n_in,
                              void* d_out, int out_size, void* d_ws, size_t ws_size,
                              hipStream_t stream) {
    const float* Ex = (const float*)d_in[0];
    const float* Ey = (const float*)d_in[1];
    float* out = (float*)d_out;
    u16* Xn = (u16*)d_ws;                // 4 MB, row-major bf16
    u16* Yn = Xn + (size_t)NROWS * DIM;  // 4 MB, row-major bf16

    hipLaunchKernelGGL(normalize_kernel, dim3(NROWS / 4, 2), dim3(256), 0, stream,
                       Ex, Ey, Xn, Yn, out);
    // grid: b&63 = row-tile (spreads A-panels across XCDs, stable per XCD),
    // b>>6 = colgroup (all XCDs sweep the same B-strip together).
    hipLaunchKernelGGL(gemm_min_kernel, dim3(64 * (NROWS / (NCT * BNT))), dim3(256), 0, stream,
                       Xn, Yn, out);
}